// Round 1
// baseline (10815.321 us; speedup 1.0000x reference)
//
#include <hip/hip_runtime.h>
#include <math.h>

// Problem constants
constexpr int D = 768;
constexpr int H = 12;
constexpr int L = 6;
constexpr int B = 8;
constexpr int S = 256;
constexpr int DH = 64;      // D/H
constexpr int M = B * S;    // 2048 rows
constexpr int D4 = 4 * D;   // 3072

// ---------------------------------------------------------------------------
// GEMM: C[M,N] = act(A[M,K] @ W[K,N] + bias[N])
// A row-major lda, W row-major ldw, C row-major ldc. M=2048 always.
// BM=BN=64, BK=16, 256 threads, 4x4 outputs per thread.
// act: 0 = none, 1 = exact gelu
// ---------------------------------------------------------------------------
__global__ __launch_bounds__(256) void gemm_kernel(
    const float* __restrict__ A, int lda,
    const float* __restrict__ W, int ldw,
    const float* __restrict__ bias,
    float* __restrict__ C, int ldc,
    int K, int act)
{
    __shared__ __align__(16) float As[16][68];  // As[k][m], padded
    __shared__ __align__(16) float Bs[16][64];  // Bs[k][n]

    const int tid = threadIdx.x;
    const int m0 = blockIdx.y * 64;
    const int n0 = blockIdx.x * 64;
    const int tx = tid & 15;   // n-dir, 0..15
    const int ty = tid >> 4;   // m-dir, 0..15

    // A load: thread -> float4 along k. m = tid/4 (0..63), k = (tid&3)*4
    const int am = tid >> 2;
    const int ak = (tid & 3) * 4;
    // B load: thread -> float4 along n. k = tid/16 (0..15), n = (tid&15)*4
    const int bk = tid >> 4;
    const int bn = (tid & 15) * 4;

    float acc[4][4] = {};

    for (int k0 = 0; k0 < K; k0 += 16) {
        float4 av = *(const float4*)(A + (size_t)(m0 + am) * lda + k0 + ak);
        float4 bv = *(const float4*)(W + (size_t)(k0 + bk) * ldw + n0 + bn);
        As[ak + 0][am] = av.x;
        As[ak + 1][am] = av.y;
        As[ak + 2][am] = av.z;
        As[ak + 3][am] = av.w;
        *(float4*)&Bs[bk][bn] = bv;
        __syncthreads();
        #pragma unroll
        for (int k = 0; k < 16; ++k) {
            float4 a = *(const float4*)&As[k][ty * 4];
            float4 b = *(const float4*)&Bs[k][tx * 4];
            acc[0][0] += a.x * b.x; acc[0][1] += a.x * b.y; acc[0][2] += a.x * b.z; acc[0][3] += a.x * b.w;
            acc[1][0] += a.y * b.x; acc[1][1] += a.y * b.y; acc[1][2] += a.y * b.z; acc[1][3] += a.y * b.w;
            acc[2][0] += a.z * b.x; acc[2][1] += a.z * b.y; acc[2][2] += a.z * b.z; acc[2][3] += a.z * b.w;
            acc[3][0] += a.w * b.x; acc[3][1] += a.w * b.y; acc[3][2] += a.w * b.z; acc[3][3] += a.w * b.w;
        }
        __syncthreads();
    }

    float4 bv = *(const float4*)(bias + n0 + tx * 4);
    const float bias4[4] = {bv.x, bv.y, bv.z, bv.w};
    #pragma unroll
    for (int i = 0; i < 4; ++i) {
        float4 o;
        float* op = &o.x;
        #pragma unroll
        for (int j = 0; j < 4; ++j) {
            float v = acc[i][j] + bias4[j];
            if (act == 1) {
                v = 0.5f * v * (1.0f + erff(v * 0.7071067811865476f));
            }
            op[j] = v;
        }
        *(float4*)(C + (size_t)(m0 + ty * 4 + i) * ldc + n0 + tx * 4) = o;
    }
}

// ---------------------------------------------------------------------------
// Attention: qkv [M, 2304] (q cols 0..767, k 768..1535, v 1536..2303)
// One wave per query; block = 4 waves (4 queries of the same (b,head)).
// grid.x = B*H*(S/4) = 6144
// hout [M, 768]: hout[b*S+q][head*64+d]
// ---------------------------------------------------------------------------
__global__ __launch_bounds__(256) void attn_kernel(
    const float* __restrict__ qkv,
    const int* __restrict__ mask,
    float* __restrict__ hout)
{
    const int blk = blockIdx.x;
    const int qt = blk & 63;          // S/4 = 64 query groups
    const int bh = blk >> 6;
    const int head = bh % H;
    const int b = bh / H;
    const int wave = threadIdx.x >> 6;
    const int lane = threadIdx.x & 63;
    const int q = qt * 4 + wave;

    __shared__ __align__(16) float Ks[64][68];
    __shared__ __align__(16) float Qs[4][68];

    // load the 4 query rows (each wave loads its own, coalesced)
    Qs[wave][lane] = qkv[(size_t)(b * S + qt * 4 + wave) * 2304 + head * DH + lane];

    const float* kbase = qkv + 768 + head * DH;
    const float* vbase = qkv + 1536 + head * DH;

    float sc[4];
    for (int t = 0; t < 4; ++t) {
        __syncthreads();
        // load K tile rows t*64 .. t*64+63 (64 x 64 floats)
        #pragma unroll
        for (int i = 0; i < 4; ++i) {
            int idx = threadIdx.x + 256 * i;   // 0..1023 float4s
            int r = idx >> 4;                  // 0..63
            int c4 = (idx & 15) * 4;
            *(float4*)&Ks[r][c4] =
                *(const float4*)(kbase + (size_t)(b * S + t * 64 + r) * 2304 + c4);
        }
        __syncthreads();
        float s = 0.f;
        #pragma unroll
        for (int i = 0; i < 16; ++i) {
            float4 qv = *(const float4*)&Qs[wave][i * 4];
            float4 kv = *(const float4*)&Ks[lane][i * 4];
            s += qv.x * kv.x + qv.y * kv.y + qv.z * kv.z + qv.w * kv.w;
        }
        s *= 0.125f;  // 1/sqrt(64)
        int mv = mask[b * S + t * 64 + lane];
        s -= 10000.0f * (1.0f - (float)mv);
        sc[t] = s;
    }

    // softmax over the 256 scores (4 per lane, distributed over 64 lanes)
    float mx = fmaxf(fmaxf(sc[0], sc[1]), fmaxf(sc[2], sc[3]));
    #pragma unroll
    for (int o = 32; o > 0; o >>= 1) mx = fmaxf(mx, __shfl_xor(mx, o, 64));
    float p[4];
    float sum = 0.f;
    #pragma unroll
    for (int t = 0; t < 4; ++t) { p[t] = expf(sc[t] - mx); sum += p[t]; }
    #pragma unroll
    for (int o = 32; o > 0; o >>= 1) sum += __shfl_xor(sum, o, 64);
    const float inv = 1.0f / sum;
    #pragma unroll
    for (int t = 0; t < 4; ++t) p[t] *= inv;

    // PV: out[d=lane] = sum_j p_j * V[j][lane]; V loads are coalesced
    float out = 0.f;
    #pragma unroll
    for (int t = 0; t < 4; ++t) {
        #pragma unroll 8
        for (int jl = 0; jl < 64; ++jl) {
            float pj = __shfl(p[t], jl, 64);
            out += pj * vbase[(size_t)(b * S + t * 64 + jl) * 2304 + lane];
        }
    }
    hout[(size_t)(b * S + q) * D + head * DH + lane] = out;
}

// ---------------------------------------------------------------------------
// Residual + LayerNorm (in-place on x): x = LN(x + h) * g + b
// One block (256 threads) per row of 768.
// ---------------------------------------------------------------------------
__global__ __launch_bounds__(256) void ln_res_kernel(
    float* __restrict__ x,
    const float* __restrict__ h,
    const float* __restrict__ g,
    const float* __restrict__ bb)
{
    const int row = blockIdx.x;
    const int tid = threadIdx.x;
    const int wave = tid >> 6;
    const int lane = tid & 63;
    __shared__ float red[4];

    float v[3];
    #pragma unroll
    for (int i = 0; i < 3; ++i) {
        int c = tid + 256 * i;
        v[i] = x[(size_t)row * D + c] + h[(size_t)row * D + c];
    }
    float s = v[0] + v[1] + v[2];
    #pragma unroll
    for (int o = 32; o > 0; o >>= 1) s += __shfl_xor(s, o, 64);
    if (lane == 0) red[wave] = s;
    __syncthreads();
    const float mean = (red[0] + red[1] + red[2] + red[3]) * (1.0f / 768.0f);

    float qs = 0.f;
    #pragma unroll
    for (int i = 0; i < 3; ++i) { float d = v[i] - mean; qs += d * d; }
    #pragma unroll
    for (int o = 32; o > 0; o >>= 1) qs += __shfl_xor(qs, o, 64);
    __syncthreads();
    if (lane == 0) red[wave] = qs;
    __syncthreads();
    const float var = (red[0] + red[1] + red[2] + red[3]) * (1.0f / 768.0f);
    const float rstd = rsqrtf(var + 1e-12f);

    #pragma unroll
    for (int i = 0; i < 3; ++i) {
        int c = tid + 256 * i;
        x[(size_t)row * D + c] = (v[i] - mean) * rstd * g[c] + bb[c];
    }
}

// ---------------------------------------------------------------------------
// Host launcher
// ---------------------------------------------------------------------------
extern "C" void kernel_launch(void* const* d_in, const int* in_sizes, int n_in,
                              void* d_out, int out_size, void* d_ws, size_t ws_size,
                              hipStream_t stream)
{
    const float* x    = (const float*)d_in[0];
    const float* y    = (const float*)d_in[1];
    const int*   xm   = (const int*)d_in[2];
    const int*   ym   = (const int*)d_in[3];
    const float* ax_w = (const float*)d_in[4];
    const float* ax_b = (const float*)d_in[5];
    const float* cx_w = (const float*)d_in[6];
    const float* cx_b = (const float*)d_in[7];
    const float* fx_w1 = (const float*)d_in[8];
    const float* fx_b1 = (const float*)d_in[9];
    const float* fx_w2 = (const float*)d_in[10];
    const float* fx_b2 = (const float*)d_in[11];
    const float* ay_w = (const float*)d_in[12];
    const float* ay_b = (const float*)d_in[13];
    const float* cy_w = (const float*)d_in[14];
    const float* cy_b = (const float*)d_in[15];
    const float* fy_w1 = (const float*)d_in[16];
    const float* fy_b1 = (const float*)d_in[17];
    const float* fy_w2 = (const float*)d_in[18];
    const float* fy_b2 = (const float*)d_in[19];
    const float* lnx_g = (const float*)d_in[20];
    const float* lnx_b = (const float*)d_in[21];
    const float* lny_g = (const float*)d_in[22];
    const float* lny_b = (const float*)d_in[23];

    float* xc = (float*)d_out;          // [M, D]
    float* yc = xc + (size_t)M * D;     // [M, D]
    float* ws0 = (float*)d_ws;          // [M, 3072] : qkv (ldc 2304) or ffn-mid
    float* hbuf = ws0 + (size_t)M * D4; // [M, D]

    hipMemcpyAsync(xc, x, (size_t)M * D * sizeof(float), hipMemcpyDeviceToDevice, stream);
    hipMemcpyAsync(yc, y, (size_t)M * D * sizeof(float), hipMemcpyDeviceToDevice, stream);

    const dim3 blk(256);
    const dim3 g_proj(D / 64, M / 64);      // N=768
    const dim3 g_ffn1(D4 / 64, M / 64);     // N=3072
    const dim3 g_attn(B * H * (S / 4));
    const dim3 g_ln(M);

    auto mhsa = [&](const float* q_src, const float* kv_src,
                    const float* w, const float* bia, const int* mask,
                    float* target, const float* ln_g, const float* ln_b) {
        // q projection
        gemm_kernel<<<g_proj, blk, 0, stream>>>(q_src, D, w, D, bia,
                                                ws0, 2304, D, 0);
        // k projection
        gemm_kernel<<<g_proj, blk, 0, stream>>>(kv_src, D, w + (size_t)D * D, D, bia + D,
                                                ws0 + 768, 2304, D, 0);
        // v projection
        gemm_kernel<<<g_proj, blk, 0, stream>>>(kv_src, D, w + 2 * (size_t)D * D, D, bia + 2 * D,
                                                ws0 + 1536, 2304, D, 0);
        attn_kernel<<<g_attn, blk, 0, stream>>>(ws0, mask, hbuf);
        ln_res_kernel<<<g_ln, blk, 0, stream>>>(target, hbuf, ln_g, ln_b);
    };

    auto ffn = [&](float* t, const float* w1, const float* b1,
                   const float* w2, const float* b2,
                   const float* ln_g, const float* ln_b) {
        gemm_kernel<<<g_ffn1, blk, 0, stream>>>(t, D, w1, D4, b1, ws0, D4, D, 1);
        gemm_kernel<<<g_proj, blk, 0, stream>>>(ws0, D4, w2, D, b2, hbuf, D, D4, 0);
        ln_res_kernel<<<g_ln, blk, 0, stream>>>(t, hbuf, ln_g, ln_b);
    };

    for (int l = 0; l < L; ++l) {
        const size_t wo = (size_t)l * 3 * D * D;
        const size_t bo = (size_t)l * 3 * D;
        const size_t f1o = (size_t)l * D * D4;
        const size_t f1bo = (size_t)l * D4;
        const size_t f2o = (size_t)l * D4 * D;
        const size_t f2bo = (size_t)l * D;

        // self-attention x
        mhsa(xc, xc, ax_w + wo, ax_b + bo, xm, xc, lnx_g + 0 * D, lnx_b + 0 * D);
        // self-attention y
        mhsa(yc, yc, ay_w + wo, ay_b + bo, ym, yc, lny_g + 0 * D, lny_b + 0 * D);
        // cross-attention x (q from xc, k/v from yc, mask = y_mask)
        mhsa(xc, yc, cx_w + wo, cx_b + bo, ym, xc, lnx_g + 1 * D, lnx_b + 1 * D);
        // cross-attention y (q from yc, k/v from xc (updated), mask = x_mask)
        mhsa(yc, xc, cy_w + wo, cy_b + bo, xm, yc, lny_g + 1 * D, lny_b + 1 * D);
        // ffn x
        ffn(xc, fx_w1 + f1o, fx_b1 + f1bo, fx_w2 + f2o, fx_b2 + f2bo,
            lnx_g + 2 * D, lnx_b + 2 * D);
        // ffn y
        ffn(yc, fy_w1 + f1o, fy_b1 + f1bo, fy_w2 + f2o, fy_b2 + f2bo,
            lny_g + 2 * D, lny_b + 2 * D);
    }
}

// Round 3
// 6421.763 us; speedup vs baseline: 1.6842x; 1.6842x over previous
//
#include <hip/hip_runtime.h>
#include <math.h>

// Problem constants
constexpr int D = 768;
constexpr int H = 12;
constexpr int L = 6;
constexpr int B = 8;
constexpr int S = 256;
constexpr int DH = 64;      // D/H
constexpr int M = B * S;    // 2048 rows
constexpr int D4 = 4 * D;   // 3072

typedef _Float16 v2h __attribute__((ext_vector_type(2)));
typedef _Float16 v4h __attribute__((ext_vector_type(4)));
typedef _Float16 v8h __attribute__((ext_vector_type(8)));
typedef __fp16 f16x2 __attribute__((ext_vector_type(2)));
typedef float v4f __attribute__((ext_vector_type(4)));

// fp32 -> hi/lo fp16 split (Markidis). hi = rtz(x); lo = rtz(x - hi).
__device__ inline void cvt_split(float x, float y, v2h& hi, v2h& lo) {
    f16x2 h = __builtin_amdgcn_cvt_pkrtz(x, y);
    float rx = x - (float)h[0];
    float ry = y - (float)h[1];
    f16x2 l = __builtin_amdgcn_cvt_pkrtz(rx, ry);
    hi = __builtin_bit_cast(v2h, h);
    lo = __builtin_bit_cast(v2h, l);
}

// ---------------------------------------------------------------------------
// Split-fp16 MFMA GEMM: C[M,N] = act(A @ W + bias)
// A: row-major [M,K] (two pointers; block uses Aq if n0 < qsplit else Akv —
//   supports cross-attention where q comes from one stream, k/v from the other)
// W: n_per_mat-wide sub-matrices [K, n_per_mat] concatenated along N
//   (QKV fused: 3 matrices of width 768; plain GEMM: n_per_mat == N)
// C: row-major [M,N]. bias indexed by global column.
// Block: 128x128 tile, 256 threads (4 waves, 2x2 of 64x64), BK=32.
// Each logical fp32 k-step of 32 = 3 MFMA(16x16x32_f16) per 16x16 tile.
// act: 0 = none, 1 = exact gelu
// ---------------------------------------------------------------------------
__global__ __launch_bounds__(256) void gemm_mfma(
    const float* __restrict__ Aq, const float* __restrict__ Akv, int qsplit,
    const float* __restrict__ Wb, const float* __restrict__ bias,
    float* __restrict__ C, int K, int N, int n_per_mat, int act)
{
    const int n0 = blockIdx.x * 128;
    const int m0 = blockIdx.y * 128;
    const float* __restrict__ A = (n0 < qsplit) ? Aq : Akv;
    const int sub = n0 / n_per_mat;
    const int nc0 = n0 - sub * n_per_mat;
    const float* __restrict__ W = Wb + (size_t)sub * K * n_per_mat;

    const int tid = threadIdx.x;
    const int lane = tid & 63;
    const int wave = tid >> 6;
    const int wm = (wave & 1) * 64;
    const int wn = (wave >> 1) * 64;

    // LDS planes: [row][k] with k contiguous, row stride 40 halves (pad +8)
    __shared__ _Float16 sm[4 * 128 * 40];
    _Float16* Ah = sm;
    _Float16* Al = sm + 128 * 40;
    _Float16* Bh = sm + 2 * 128 * 40;
    _Float16* Bl = sm + 3 * 128 * 40;

    v4f acc[4][4];
    #pragma unroll
    for (int i = 0; i < 4; ++i)
        #pragma unroll
        for (int j = 0; j < 4; ++j)
            acc[i][j] = (v4f){0.f, 0.f, 0.f, 0.f};

    // A staging: thread -> rows (tid>>3)+32i, cols (tid&7)*4 .. +3 (float4)
    const int ar = tid >> 3;
    const int ac = (tid & 7) * 4;
    // B staging: thread -> col (tid&127), k-run (tid>>7)*16 .. +15 (scalar, coalesced)
    const int bn = tid & 127;
    const int bk0 = (tid >> 7) * 16;

    const int fm = lane & 15;          // fragment row/col within 16
    const int fk = (lane >> 4) * 8;    // fragment k-offset

    for (int k0 = 0; k0 < K; k0 += 32) {
        // ---- global loads (no LDS) ----
        float4 av[4];
        #pragma unroll
        for (int i = 0; i < 4; ++i)
            av[i] = *(const float4*)(A + (size_t)(m0 + ar + 32 * i) * K + k0 + ac);
        float bv[16];
        #pragma unroll
        for (int j = 0; j < 16; ++j)
            bv[j] = W[(size_t)(k0 + bk0 + j) * n_per_mat + nc0 + bn];

        __syncthreads();   // previous iteration's fragment reads done

        // ---- convert + LDS write ----
        #pragma unroll
        for (int i = 0; i < 4; ++i) {
            v2h h0, l0, h1, l1;
            cvt_split(av[i].x, av[i].y, h0, l0);
            cvt_split(av[i].z, av[i].w, h1, l1);
            v4h hh, ll;
            hh[0] = h0[0]; hh[1] = h0[1]; hh[2] = h1[0]; hh[3] = h1[1];
            ll[0] = l0[0]; ll[1] = l0[1]; ll[2] = l1[0]; ll[3] = l1[1];
            *(v4h*)&Ah[(ar + 32 * i) * 40 + ac] = hh;
            *(v4h*)&Al[(ar + 32 * i) * 40 + ac] = ll;
        }
        {
            v8h bha, bhb, bla, blb;
            #pragma unroll
            for (int j = 0; j < 4; ++j) {
                v2h h, l;
                cvt_split(bv[2 * j], bv[2 * j + 1], h, l);
                bha[2 * j] = h[0]; bha[2 * j + 1] = h[1];
                bla[2 * j] = l[0]; bla[2 * j + 1] = l[1];
            }
            #pragma unroll
            for (int j = 0; j < 4; ++j) {
                v2h h, l;
                cvt_split(bv[8 + 2 * j], bv[8 + 2 * j + 1], h, l);
                bhb[2 * j] = h[0]; bhb[2 * j + 1] = h[1];
                blb[2 * j] = l[0]; blb[2 * j + 1] = l[1];
            }
            *(v8h*)&Bh[bn * 40 + bk0] = bha;
            *(v8h*)&Bh[bn * 40 + bk0 + 8] = bhb;
            *(v8h*)&Bl[bn * 40 + bk0] = bla;
            *(v8h*)&Bl[bn * 40 + bk0 + 8] = blb;
        }
        __syncthreads();   // writes visible

        // ---- fragments + MFMA ----
        v8h fah[4], fal[4], fbh[4], fbl[4];
        #pragma unroll
        for (int i = 0; i < 4; ++i) {
            fah[i] = *(v8h*)&Ah[(wm + i * 16 + fm) * 40 + fk];
            fal[i] = *(v8h*)&Al[(wm + i * 16 + fm) * 40 + fk];
        }
        #pragma unroll
        for (int j = 0; j < 4; ++j) {
            fbh[j] = *(v8h*)&Bh[(wn + j * 16 + fm) * 40 + fk];
            fbl[j] = *(v8h*)&Bl[(wn + j * 16 + fm) * 40 + fk];
        }
        #pragma unroll
        for (int i = 0; i < 4; ++i)
            #pragma unroll
            for (int j = 0; j < 4; ++j) {
                acc[i][j] = __builtin_amdgcn_mfma_f32_16x16x32_f16(fah[i], fbh[j], acc[i][j], 0, 0, 0);
                acc[i][j] = __builtin_amdgcn_mfma_f32_16x16x32_f16(fah[i], fbl[j], acc[i][j], 0, 0, 0);
                acc[i][j] = __builtin_amdgcn_mfma_f32_16x16x32_f16(fal[i], fbh[j], acc[i][j], 0, 0, 0);
            }
    }

    // ---- epilogue: bias + optional gelu, store fp32 ----
    const int er = (lane >> 4) * 4;   // C row base within tile
    const int ec = lane & 15;         // C col within tile
    #pragma unroll
    for (int j = 0; j < 4; ++j) {
        const int col = n0 + wn + j * 16 + ec;
        const float bs = bias[col];
        #pragma unroll
        for (int i = 0; i < 4; ++i) {
            #pragma unroll
            for (int r = 0; r < 4; ++r) {
                const int row = m0 + wm + i * 16 + er + r;
                float v = acc[i][j][r] + bs;
                if (act == 1)
                    v = 0.5f * v * (1.0f + erff(v * 0.7071067811865476f));
                C[(size_t)row * N + col] = v;
            }
        }
    }
}

// ---------------------------------------------------------------------------
// Attention: qkv [M, 2304] (q cols 0..767, k 768..1535, v 1536..2303)
// One wave per query; block = 4 waves. grid.x = B*H*(S/4) = 6144
// ---------------------------------------------------------------------------
__global__ __launch_bounds__(256) void attn_kernel(
    const float* __restrict__ qkv,
    const int* __restrict__ mask,
    float* __restrict__ hout)
{
    const int blk = blockIdx.x;
    const int qt = blk & 63;
    const int bh = blk >> 6;
    const int head = bh % H;
    const int b = bh / H;
    const int wave = threadIdx.x >> 6;
    const int lane = threadIdx.x & 63;
    const int q = qt * 4 + wave;

    __shared__ __align__(16) float Ks[64][68];
    __shared__ __align__(16) float Qs[4][68];

    Qs[wave][lane] = qkv[(size_t)(b * S + qt * 4 + wave) * 2304 + head * DH + lane];

    const float* kbase = qkv + 768 + head * DH;
    const float* vbase = qkv + 1536 + head * DH;

    float sc[4];
    for (int t = 0; t < 4; ++t) {
        __syncthreads();
        #pragma unroll
        for (int i = 0; i < 4; ++i) {
            int idx = threadIdx.x + 256 * i;
            int r = idx >> 4;
            int c4 = (idx & 15) * 4;
            *(float4*)&Ks[r][c4] =
                *(const float4*)(kbase + (size_t)(b * S + t * 64 + r) * 2304 + c4);
        }
        __syncthreads();
        float s = 0.f;
        #pragma unroll
        for (int i = 0; i < 16; ++i) {
            float4 qv = *(const float4*)&Qs[wave][i * 4];
            float4 kv = *(const float4*)&Ks[lane][i * 4];
            s += qv.x * kv.x + qv.y * kv.y + qv.z * kv.z + qv.w * kv.w;
        }
        s *= 0.125f;
        int mv = mask[b * S + t * 64 + lane];
        s -= 10000.0f * (1.0f - (float)mv);
        sc[t] = s;
    }

    float mx = fmaxf(fmaxf(sc[0], sc[1]), fmaxf(sc[2], sc[3]));
    #pragma unroll
    for (int o = 32; o > 0; o >>= 1) mx = fmaxf(mx, __shfl_xor(mx, o, 64));
    float p[4];
    float sum = 0.f;
    #pragma unroll
    for (int t = 0; t < 4; ++t) { p[t] = expf(sc[t] - mx); sum += p[t]; }
    #pragma unroll
    for (int o = 32; o > 0; o >>= 1) sum += __shfl_xor(sum, o, 64);
    const float inv = 1.0f / sum;
    #pragma unroll
    for (int t = 0; t < 4; ++t) p[t] *= inv;

    float out = 0.f;
    #pragma unroll
    for (int t = 0; t < 4; ++t) {
        #pragma unroll 8
        for (int jl = 0; jl < 64; ++jl) {
            float pj = __shfl(p[t], jl, 64);
            out += pj * vbase[(size_t)(b * S + t * 64 + jl) * 2304 + lane];
        }
    }
    hout[(size_t)(b * S + q) * D + head * DH + lane] = out;
}

// ---------------------------------------------------------------------------
// Residual + LayerNorm (in-place on x): x = LN(x + h) * g + b
// ---------------------------------------------------------------------------
__global__ __launch_bounds__(256) void ln_res_kernel(
    float* __restrict__ x,
    const float* __restrict__ h,
    const float* __restrict__ g,
    const float* __restrict__ bb)
{
    const int row = blockIdx.x;
    const int tid = threadIdx.x;
    const int wave = tid >> 6;
    const int lane = tid & 63;
    __shared__ float red[4];

    float v[3];
    #pragma unroll
    for (int i = 0; i < 3; ++i) {
        int c = tid + 256 * i;
        v[i] = x[(size_t)row * D + c] + h[(size_t)row * D + c];
    }
    float s = v[0] + v[1] + v[2];
    #pragma unroll
    for (int o = 32; o > 0; o >>= 1) s += __shfl_xor(s, o, 64);
    if (lane == 0) red[wave] = s;
    __syncthreads();
    const float mean = (red[0] + red[1] + red[2] + red[3]) * (1.0f / 768.0f);

    float qs = 0.f;
    #pragma unroll
    for (int i = 0; i < 3; ++i) { float d = v[i] - mean; qs += d * d; }
    #pragma unroll
    for (int o = 32; o > 0; o >>= 1) qs += __shfl_xor(qs, o, 64);
    __syncthreads();
    if (lane == 0) red[wave] = qs;
    __syncthreads();
    const float var = (red[0] + red[1] + red[2] + red[3]) * (1.0f / 768.0f);
    const float rstd = rsqrtf(var + 1e-12f);

    #pragma unroll
    for (int i = 0; i < 3; ++i) {
        int c = tid + 256 * i;
        x[(size_t)row * D + c] = (v[i] - mean) * rstd * g[c] + bb[c];
    }
}

// ---------------------------------------------------------------------------
// Host launcher
// ---------------------------------------------------------------------------
extern "C" void kernel_launch(void* const* d_in, const int* in_sizes, int n_in,
                              void* d_out, int out_size, void* d_ws, size_t ws_size,
                              hipStream_t stream)
{
    const float* x    = (const float*)d_in[0];
    const float* y    = (const float*)d_in[1];
    const int*   xm   = (const int*)d_in[2];
    const int*   ym   = (const int*)d_in[3];
    const float* ax_w = (const float*)d_in[4];
    const float* ax_b = (const float*)d_in[5];
    const float* cx_w = (const float*)d_in[6];
    const float* cx_b = (const float*)d_in[7];
    const float* fx_w1 = (const float*)d_in[8];
    const float* fx_b1 = (const float*)d_in[9];
    const float* fx_w2 = (const float*)d_in[10];
    const float* fx_b2 = (const float*)d_in[11];
    const float* ay_w = (const float*)d_in[12];
    const float* ay_b = (const float*)d_in[13];
    const float* cy_w = (const float*)d_in[14];
    const float* cy_b = (const float*)d_in[15];
    const float* fy_w1 = (const float*)d_in[16];
    const float* fy_b1 = (const float*)d_in[17];
    const float* fy_w2 = (const float*)d_in[18];
    const float* fy_b2 = (const float*)d_in[19];
    const float* lnx_g = (const float*)d_in[20];
    const float* lnx_b = (const float*)d_in[21];
    const float* lny_g = (const float*)d_in[22];
    const float* lny_b = (const float*)d_in[23];

    float* xc = (float*)d_out;
    float* yc = xc + (size_t)M * D;
    float* ws0 = (float*)d_ws;          // [M, 3072]: fused qkv (ld 2304) or ffn mid
    float* hbuf = ws0 + (size_t)M * D4; // [M, D]

    (void)hipMemcpyAsync(xc, x, (size_t)M * D * sizeof(float), hipMemcpyDeviceToDevice, stream);
    (void)hipMemcpyAsync(yc, y, (size_t)M * D * sizeof(float), hipMemcpyDeviceToDevice, stream);

    const dim3 blk(256);
    const dim3 g_qkv(2304 / 128, M / 128);   // 18 x 16
    const dim3 g_ffn1(D4 / 128, M / 128);    // 24 x 16
    const dim3 g_ffn2(D / 128, M / 128);     // 6 x 16
    const dim3 g_attn(B * H * (S / 4));
    const dim3 g_ln(M);

    // fused qkv projection + attention + residual-LN
    auto mhsa = [&](const float* q_src, const float* kv_src,
                    const float* w, const float* bia, const int* mask,
                    float* target, const float* ln_g, const float* ln_b) {
        gemm_mfma<<<g_qkv, blk, 0, stream>>>(q_src, kv_src, 768, w, bia,
                                             ws0, D, 2304, 768, 0);
        attn_kernel<<<g_attn, blk, 0, stream>>>(ws0, mask, hbuf);
        ln_res_kernel<<<g_ln, blk, 0, stream>>>(target, hbuf, ln_g, ln_b);
    };

    auto ffn = [&](float* t, const float* w1, const float* b1,
                   const float* w2, const float* b2,
                   const float* ln_g, const float* ln_b) {
        gemm_mfma<<<g_ffn1, blk, 0, stream>>>(t, t, 0, w1, b1, ws0, D, D4, D4, 1);
        gemm_mfma<<<g_ffn2, blk, 0, stream>>>(ws0, ws0, 0, w2, b2, hbuf, D4, D, D, 0);
        ln_res_kernel<<<g_ln, blk, 0, stream>>>(t, hbuf, ln_g, ln_b);
    };

    for (int l = 0; l < L; ++l) {
        const size_t wo = (size_t)l * 3 * D * D;
        const size_t bo = (size_t)l * 3 * D;
        const size_t f1o = (size_t)l * D * D4;
        const size_t f1bo = (size_t)l * D4;
        const size_t f2o = (size_t)l * D4 * D;
        const size_t f2bo = (size_t)l * D;

        mhsa(xc, xc, ax_w + wo, ax_b + bo, xm, xc, lnx_g + 0 * D, lnx_b + 0 * D);
        mhsa(yc, yc, ay_w + wo, ay_b + bo, ym, yc, lny_g + 0 * D, lny_b + 0 * D);
        // cross-x: q from xc, k/v from yc (mask = y_mask)
        mhsa(xc, yc, cx_w + wo, cx_b + bo, ym, xc, lnx_g + 1 * D, lnx_b + 1 * D);
        // cross-y: q from yc, k/v from updated xc (mask = x_mask)
        mhsa(yc, xc, cy_w + wo, cy_b + bo, xm, yc, lny_g + 1 * D, lny_b + 1 * D);
        ffn(xc, fx_w1 + f1o, fx_b1 + f1bo, fx_w2 + f2o, fx_b2 + f2bo,
            lnx_g + 2 * D, lnx_b + 2 * D);
        ffn(yc, fy_w1 + f1o, fy_b1 + f1bo, fy_w2 + f2o, fy_b2 + f2bo,
            lny_g + 2 * D, lny_b + 2 * D);
    }
}

// Round 4
// 5515.236 us; speedup vs baseline: 1.9610x; 1.1644x over previous
//
#include <hip/hip_runtime.h>
#include <math.h>

// Problem constants
constexpr int D = 768;
constexpr int H = 12;
constexpr int L = 6;
constexpr int B = 8;
constexpr int S = 256;
constexpr int DH = 64;      // D/H
constexpr int M = B * S;    // 2048 rows
constexpr int D4 = 4 * D;   // 3072

typedef _Float16 v2h __attribute__((ext_vector_type(2)));
typedef _Float16 v4h __attribute__((ext_vector_type(4)));
typedef _Float16 v8h __attribute__((ext_vector_type(8)));
typedef __fp16 f16x2 __attribute__((ext_vector_type(2)));
typedef float v4f __attribute__((ext_vector_type(4)));

// fp32 -> hi/lo fp16 split (Markidis). hi = rtz(x); lo = rtz(x - hi).
__device__ inline void cvt_split(float x, float y, v2h& hi, v2h& lo) {
    f16x2 h = __builtin_amdgcn_cvt_pkrtz(x, y);
    float rx = x - (float)h[0];
    float ry = y - (float)h[1];
    f16x2 l = __builtin_amdgcn_cvt_pkrtz(rx, ry);
    hi = __builtin_bit_cast(v2h, h);
    lo = __builtin_bit_cast(v2h, l);
}

// ---------------------------------------------------------------------------
// Split-fp16 MFMA GEMM, software-pipelined, dual-stream (blockIdx.z).
// C[M,N] = act(A @ W + bias).  A row-major [M,K]; per-block A = Aq if
// n0 < qsplit else Akv (cross-attention support). W = n_per_mat-wide
// sub-matrices [K, n_per_mat] concatenated along N.
// Block: 128x128 tile, 256 threads (4 waves, 2x2 of 64x64), BK=32.
// ---------------------------------------------------------------------------
__global__ __launch_bounds__(256) void gemm_mfma(
    const float* __restrict__ Aq0, const float* __restrict__ Akv0,
    const float* __restrict__ W0,  const float* __restrict__ bias0, float* __restrict__ C0,
    const float* __restrict__ Aq1, const float* __restrict__ Akv1,
    const float* __restrict__ W1,  const float* __restrict__ bias1, float* __restrict__ C1,
    int qsplit, int K, int N, int n_per_mat, int act)
{
    const int z = blockIdx.z;
    const float* __restrict__ Aq  = z ? Aq1  : Aq0;
    const float* __restrict__ Akv = z ? Akv1 : Akv0;
    const float* __restrict__ Wb  = z ? W1   : W0;
    const float* __restrict__ bias = z ? bias1 : bias0;
    float* __restrict__ C = z ? C1 : C0;

    const int n0 = blockIdx.x * 128;
    const int m0 = blockIdx.y * 128;
    const float* __restrict__ A = (n0 < qsplit) ? Aq : Akv;
    const int sub = n0 / n_per_mat;
    const int nc0 = n0 - sub * n_per_mat;
    const float* __restrict__ W = Wb + (size_t)sub * K * n_per_mat;

    const int tid = threadIdx.x;
    const int lane = tid & 63;
    const int wave = tid >> 6;
    const int wm = (wave & 1) * 64;
    const int wn = (wave >> 1) * 64;

    // LDS planes: [row][k], row stride 40 halves
    __shared__ _Float16 sm[4 * 128 * 40];
    _Float16* Ah = sm;
    _Float16* Al = sm + 128 * 40;
    _Float16* Bh = sm + 2 * 128 * 40;
    _Float16* Bl = sm + 3 * 128 * 40;

    v4f acc[4][4];
    #pragma unroll
    for (int i = 0; i < 4; ++i)
        #pragma unroll
        for (int j = 0; j < 4; ++j)
            acc[i][j] = (v4f){0.f, 0.f, 0.f, 0.f};

    const int ar = tid >> 3;            // A row 0..31 (+32i)
    const int ac = (tid & 7) * 4;       // A k-col (float4)
    const int bn = tid & 127;           // B col
    const int bk0 = (tid >> 7) * 16;    // B k-row base

    const int fm = lane & 15;
    const int fk = (lane >> 4) * 8;

    float4 av[4];
    float bv[16];
    // prologue load (k0 = 0)
    #pragma unroll
    for (int i = 0; i < 4; ++i)
        av[i] = *(const float4*)(A + (size_t)(m0 + ar + 32 * i) * K + ac);
    #pragma unroll
    for (int j = 0; j < 16; ++j)
        bv[j] = W[(size_t)(bk0 + j) * n_per_mat + nc0 + bn];

    for (int k0 = 0; k0 < K; k0 += 32) {
        // ---- issue next iteration's global loads early ----
        float4 av2[4];
        float bv2[16];
        if (k0 + 32 < K) {
            #pragma unroll
            for (int i = 0; i < 4; ++i)
                av2[i] = *(const float4*)(A + (size_t)(m0 + ar + 32 * i) * K + k0 + 32 + ac);
            #pragma unroll
            for (int j = 0; j < 16; ++j)
                bv2[j] = W[(size_t)(k0 + 32 + bk0 + j) * n_per_mat + nc0 + bn];
        }

        __syncthreads();   // previous iteration's fragment reads done

        // ---- convert current + LDS write ----
        #pragma unroll
        for (int i = 0; i < 4; ++i) {
            v2h h0, l0, h1, l1;
            cvt_split(av[i].x, av[i].y, h0, l0);
            cvt_split(av[i].z, av[i].w, h1, l1);
            v4h hh, ll;
            hh[0] = h0[0]; hh[1] = h0[1]; hh[2] = h1[0]; hh[3] = h1[1];
            ll[0] = l0[0]; ll[1] = l0[1]; ll[2] = l1[0]; ll[3] = l1[1];
            *(v4h*)&Ah[(ar + 32 * i) * 40 + ac] = hh;
            *(v4h*)&Al[(ar + 32 * i) * 40 + ac] = ll;
        }
        {
            v8h bha, bhb, bla, blb;
            #pragma unroll
            for (int j = 0; j < 4; ++j) {
                v2h h, l;
                cvt_split(bv[2 * j], bv[2 * j + 1], h, l);
                bha[2 * j] = h[0]; bha[2 * j + 1] = h[1];
                bla[2 * j] = l[0]; bla[2 * j + 1] = l[1];
            }
            #pragma unroll
            for (int j = 0; j < 4; ++j) {
                v2h h, l;
                cvt_split(bv[8 + 2 * j], bv[8 + 2 * j + 1], h, l);
                bhb[2 * j] = h[0]; bhb[2 * j + 1] = h[1];
                blb[2 * j] = l[0]; blb[2 * j + 1] = l[1];
            }
            *(v8h*)&Bh[bn * 40 + bk0] = bha;
            *(v8h*)&Bh[bn * 40 + bk0 + 8] = bhb;
            *(v8h*)&Bl[bn * 40 + bk0] = bla;
            *(v8h*)&Bl[bn * 40 + bk0 + 8] = blb;
        }
        __syncthreads();

        // ---- fragments + MFMA ----
        v8h fah[4], fal[4], fbh[4], fbl[4];
        #pragma unroll
        for (int i = 0; i < 4; ++i) {
            fah[i] = *(v8h*)&Ah[(wm + i * 16 + fm) * 40 + fk];
            fal[i] = *(v8h*)&Al[(wm + i * 16 + fm) * 40 + fk];
        }
        #pragma unroll
        for (int j = 0; j < 4; ++j) {
            fbh[j] = *(v8h*)&Bh[(wn + j * 16 + fm) * 40 + fk];
            fbl[j] = *(v8h*)&Bl[(wn + j * 16 + fm) * 40 + fk];
        }
        #pragma unroll
        for (int i = 0; i < 4; ++i)
            #pragma unroll
            for (int j = 0; j < 4; ++j) {
                acc[i][j] = __builtin_amdgcn_mfma_f32_16x16x32_f16(fah[i], fbh[j], acc[i][j], 0, 0, 0);
                acc[i][j] = __builtin_amdgcn_mfma_f32_16x16x32_f16(fah[i], fbl[j], acc[i][j], 0, 0, 0);
                acc[i][j] = __builtin_amdgcn_mfma_f32_16x16x32_f16(fal[i], fbh[j], acc[i][j], 0, 0, 0);
            }

        #pragma unroll
        for (int i = 0; i < 4; ++i) av[i] = av2[i];
        #pragma unroll
        for (int j = 0; j < 16; ++j) bv[j] = bv2[j];
    }

    // ---- epilogue ----
    const int er = (lane >> 4) * 4;
    const int ec = lane & 15;
    #pragma unroll
    for (int j = 0; j < 4; ++j) {
        const int col = n0 + wn + j * 16 + ec;
        const float bs = bias[col];
        #pragma unroll
        for (int i = 0; i < 4; ++i) {
            #pragma unroll
            for (int r = 0; r < 4; ++r) {
                const int row = m0 + wm + i * 16 + er + r;
                float v = acc[i][j][r] + bs;
                if (act == 1)
                    v = 0.5f * v * (1.0f + erff(v * 0.7071067811865476f));
                C[(size_t)row * N + col] = v;
            }
        }
    }
}

// ---------------------------------------------------------------------------
// Attention, dual-stream (blockIdx.z). qkv [M,2304]; 2 queries per wave;
// block = 4 waves = 8 queries. grid.x = B*H*(S/8) = 3072.
// K-tile in LDS with 16B-block rotation swizzle (stride 64, 4-way max).
// ---------------------------------------------------------------------------
__global__ __launch_bounds__(256) void attn_kernel(
    const float* __restrict__ qkv0, const int* __restrict__ mask0, float* __restrict__ hout0,
    const float* __restrict__ qkv1, const int* __restrict__ mask1, float* __restrict__ hout1)
{
    const float* __restrict__ qkv = blockIdx.z ? qkv1 : qkv0;
    const int* __restrict__ mask = blockIdx.z ? mask1 : mask0;
    float* __restrict__ hout = blockIdx.z ? hout1 : hout0;

    const int blk = blockIdx.x;
    const int qt = blk & 31;          // S/8 = 32 query groups
    const int bh = blk >> 5;
    const int head = bh % H;
    const int b = bh / H;
    const int wave = threadIdx.x >> 6;
    const int lane = threadIdx.x & 63;
    const int q0 = qt * 8 + wave * 2;

    __shared__ __align__(16) float Ks[64][64];   // swizzled
    __shared__ __align__(16) float Qs[8][68];

    Qs[wave * 2 + 0][lane] = qkv[(size_t)(b * S + q0 + 0) * 2304 + head * DH + lane];
    Qs[wave * 2 + 1][lane] = qkv[(size_t)(b * S + q0 + 1) * 2304 + head * DH + lane];

    const float* kbase = qkv + 768 + head * DH;
    const float* vbase = qkv + 1536 + head * DH;

    float sc0[4], sc1[4];
    for (int t = 0; t < 4; ++t) {
        __syncthreads();
        #pragma unroll
        for (int i = 0; i < 4; ++i) {
            int idx = threadIdx.x + 256 * i;
            int r = idx >> 4;
            int cb = idx & 15;                       // logical 16B block
            int pb = (cb + r) & 15;                  // physical (swizzled)
            *(float4*)&Ks[r][pb * 4] =
                *(const float4*)(kbase + (size_t)(b * S + t * 64 + r) * 2304 + cb * 4);
        }
        __syncthreads();
        float s0 = 0.f, s1 = 0.f;
        #pragma unroll
        for (int i = 0; i < 16; ++i) {
            int pb = (i + lane) & 15;                // physical block holding logical i
            float4 kv = *(const float4*)&Ks[lane][pb * 4];
            float4 qa = *(const float4*)&Qs[wave * 2 + 0][i * 4];
            float4 qb = *(const float4*)&Qs[wave * 2 + 1][i * 4];
            s0 += qa.x * kv.x + qa.y * kv.y + qa.z * kv.z + qa.w * kv.w;
            s1 += qb.x * kv.x + qb.y * kv.y + qb.z * kv.z + qb.w * kv.w;
        }
        const float mpen = -10000.0f * (1.0f - (float)mask[b * S + t * 64 + lane]);
        sc0[t] = s0 * 0.125f + mpen;
        sc1[t] = s1 * 0.125f + mpen;
    }

    // softmax (per query, distributed over 64 lanes x 4 tiles)
    float mx0 = fmaxf(fmaxf(sc0[0], sc0[1]), fmaxf(sc0[2], sc0[3]));
    float mx1 = fmaxf(fmaxf(sc1[0], sc1[1]), fmaxf(sc1[2], sc1[3]));
    #pragma unroll
    for (int o = 32; o > 0; o >>= 1) {
        mx0 = fmaxf(mx0, __shfl_xor(mx0, o, 64));
        mx1 = fmaxf(mx1, __shfl_xor(mx1, o, 64));
    }
    float p0[4], p1[4];
    float sum0 = 0.f, sum1 = 0.f;
    #pragma unroll
    for (int t = 0; t < 4; ++t) {
        p0[t] = expf(sc0[t] - mx0); sum0 += p0[t];
        p1[t] = expf(sc1[t] - mx1); sum1 += p1[t];
    }
    #pragma unroll
    for (int o = 32; o > 0; o >>= 1) {
        sum0 += __shfl_xor(sum0, o, 64);
        sum1 += __shfl_xor(sum1, o, 64);
    }
    const float inv0 = 1.0f / sum0;
    const float inv1 = 1.0f / sum1;
    #pragma unroll
    for (int t = 0; t < 4; ++t) { p0[t] *= inv0; p1[t] *= inv1; }

    // PV: one V load feeds both queries
    float out0 = 0.f, out1 = 0.f;
    #pragma unroll
    for (int t = 0; t < 4; ++t) {
        #pragma unroll 8
        for (int jl = 0; jl < 64; ++jl) {
            float v = vbase[(size_t)(b * S + t * 64 + jl) * 2304 + lane];
            out0 += __shfl(p0[t], jl, 64) * v;
            out1 += __shfl(p1[t], jl, 64) * v;
        }
    }
    hout[(size_t)(b * S + q0 + 0) * D + head * DH + lane] = out0;
    hout[(size_t)(b * S + q0 + 1) * D + head * DH + lane] = out1;
}

// ---------------------------------------------------------------------------
// Residual + LayerNorm (in-place), dual-stream via blockIdx.y.
// ---------------------------------------------------------------------------
__global__ __launch_bounds__(256) void ln_res_kernel(
    float* __restrict__ x0, const float* __restrict__ h0,
    const float* __restrict__ g0, const float* __restrict__ bb0,
    float* __restrict__ x1, const float* __restrict__ h1,
    const float* __restrict__ g1, const float* __restrict__ bb1)
{
    float* __restrict__ x = blockIdx.y ? x1 : x0;
    const float* __restrict__ h = blockIdx.y ? h1 : h0;
    const float* __restrict__ g = blockIdx.y ? g1 : g0;
    const float* __restrict__ bb = blockIdx.y ? bb1 : bb0;

    const int row = blockIdx.x;
    const int tid = threadIdx.x;
    const int wave = tid >> 6;
    const int lane = tid & 63;
    __shared__ float red[4];

    float v[3];
    #pragma unroll
    for (int i = 0; i < 3; ++i) {
        int c = tid + 256 * i;
        v[i] = x[(size_t)row * D + c] + h[(size_t)row * D + c];
    }
    float s = v[0] + v[1] + v[2];
    #pragma unroll
    for (int o = 32; o > 0; o >>= 1) s += __shfl_xor(s, o, 64);
    if (lane == 0) red[wave] = s;
    __syncthreads();
    const float mean = (red[0] + red[1] + red[2] + red[3]) * (1.0f / 768.0f);

    float qs = 0.f;
    #pragma unroll
    for (int i = 0; i < 3; ++i) { float d = v[i] - mean; qs += d * d; }
    #pragma unroll
    for (int o = 32; o > 0; o >>= 1) qs += __shfl_xor(qs, o, 64);
    __syncthreads();
    if (lane == 0) red[wave] = qs;
    __syncthreads();
    const float var = (red[0] + red[1] + red[2] + red[3]) * (1.0f / 768.0f);
    const float rstd = rsqrtf(var + 1e-12f);

    #pragma unroll
    for (int i = 0; i < 3; ++i) {
        int c = tid + 256 * i;
        x[(size_t)row * D + c] = (v[i] - mean) * rstd * g[c] + bb[c];
    }
}

// ---------------------------------------------------------------------------
// Host launcher
// ---------------------------------------------------------------------------
extern "C" void kernel_launch(void* const* d_in, const int* in_sizes, int n_in,
                              void* d_out, int out_size, void* d_ws, size_t ws_size,
                              hipStream_t stream)
{
    const float* x    = (const float*)d_in[0];
    const float* y    = (const float*)d_in[1];
    const int*   xm   = (const int*)d_in[2];
    const int*   ym   = (const int*)d_in[3];
    const float* ax_w = (const float*)d_in[4];
    const float* ax_b = (const float*)d_in[5];
    const float* cx_w = (const float*)d_in[6];
    const float* cx_b = (const float*)d_in[7];
    const float* fx_w1 = (const float*)d_in[8];
    const float* fx_b1 = (const float*)d_in[9];
    const float* fx_w2 = (const float*)d_in[10];
    const float* fx_b2 = (const float*)d_in[11];
    const float* ay_w = (const float*)d_in[12];
    const float* ay_b = (const float*)d_in[13];
    const float* cy_w = (const float*)d_in[14];
    const float* cy_b = (const float*)d_in[15];
    const float* fy_w1 = (const float*)d_in[16];
    const float* fy_b1 = (const float*)d_in[17];
    const float* fy_w2 = (const float*)d_in[18];
    const float* fy_b2 = (const float*)d_in[19];
    const float* lnx_g = (const float*)d_in[20];
    const float* lnx_b = (const float*)d_in[21];
    const float* lny_g = (const float*)d_in[22];
    const float* lny_b = (const float*)d_in[23];

    float* xc = (float*)d_out;
    float* yc = xc + (size_t)M * D;

    // Workspace layout. Big (merged) path needs 2 qkv/ffn-mid buffers + 2 hbufs.
    const size_t need = ((size_t)2 * M * D4 + (size_t)2 * M * D) * sizeof(float);
    const bool big = ws_size >= need;
    float* ws0 = (float*)d_ws;
    float* qkvx = ws0;
    float* qkvy = big ? ws0 + (size_t)M * D4 : ws0;
    float* hbx = ws0 + (big ? (size_t)2 * M * D4 : (size_t)M * D4);
    float* hby = big ? hbx + (size_t)M * D : hbx;

    (void)hipMemcpyAsync(xc, x, (size_t)M * D * sizeof(float), hipMemcpyDeviceToDevice, stream);
    (void)hipMemcpyAsync(yc, y, (size_t)M * D * sizeof(float), hipMemcpyDeviceToDevice, stream);

    const dim3 blk(256);

    auto qkv_gemm = [&](const float* aq0, const float* akv0, const float* w0, const float* bi0, float* c0,
                        const float* aq1, const float* akv1, const float* w1, const float* bi1, float* c1,
                        int nz) {
        gemm_mfma<<<dim3(2304 / 128, M / 128, nz), blk, 0, stream>>>(
            aq0, akv0, w0, bi0, c0, aq1, akv1, w1, bi1, c1, 768, D, 2304, 768, 0);
    };
    auto ffn1_gemm = [&](const float* a0, const float* w0, const float* bi0, float* c0,
                         const float* a1, const float* w1, const float* bi1, float* c1, int nz) {
        gemm_mfma<<<dim3(D4 / 128, M / 128, nz), blk, 0, stream>>>(
            a0, a0, w0, bi0, c0, a1, a1, w1, bi1, c1, 0, D, D4, D4, 1);
    };
    auto ffn2_gemm = [&](const float* a0, const float* w0, const float* bi0, float* c0,
                         const float* a1, const float* w1, const float* bi1, float* c1, int nz) {
        gemm_mfma<<<dim3(D / 128, M / 128, nz), blk, 0, stream>>>(
            a0, a0, w0, bi0, c0, a1, a1, w1, bi1, c1, 0, D4, D, D, 0);
    };
    auto attn = [&](const float* q0, const int* m0_, float* h0,
                    const float* q1, const int* m1_, float* h1, int nz) {
        attn_kernel<<<dim3(B * H * (S / 8), 1, nz), blk, 0, stream>>>(q0, m0_, h0, q1, m1_, h1);
    };
    auto ln = [&](float* x0, const float* h0, const float* g0, const float* b0,
                  float* x1, const float* h1, const float* g1, const float* b1, int ny) {
        ln_res_kernel<<<dim3(M, ny), blk, 0, stream>>>(x0, h0, g0, b0, x1, h1, g1, b1);
    };

    for (int l = 0; l < L; ++l) {
        const size_t wo = (size_t)l * 3 * D * D;
        const size_t bo = (size_t)l * 3 * D;
        const size_t f1o = (size_t)l * D * D4;
        const size_t f1bo = (size_t)l * D4;
        const size_t f2o = (size_t)l * D4 * D;
        const size_t f2bo = (size_t)l * D;

        if (big) {
            // self-attention x & y merged
            qkv_gemm(xc, xc, ax_w + wo, ax_b + bo, qkvx,
                     yc, yc, ay_w + wo, ay_b + bo, qkvy, 2);
            attn(qkvx, xm, hbx, qkvy, ym, hby, 2);
            ln(xc, hbx, lnx_g, lnx_b, yc, hby, lny_g, lny_b, 2);
            // cross-x (q from xc, kv from yc, mask ym)
            qkv_gemm(xc, yc, cx_w + wo, cx_b + bo, qkvx,
                     xc, yc, cx_w + wo, cx_b + bo, qkvx, 1);
            attn(qkvx, ym, hbx, qkvx, ym, hbx, 1);
            ln(xc, hbx, lnx_g + D, lnx_b + D, xc, hbx, lnx_g + D, lnx_b + D, 1);
            // cross-y (q from yc, kv from updated xc, mask xm)
            qkv_gemm(yc, xc, cy_w + wo, cy_b + bo, qkvy,
                     yc, xc, cy_w + wo, cy_b + bo, qkvy, 1);
            attn(qkvy, xm, hby, qkvy, xm, hby, 1);
            ln(yc, hby, lny_g + D, lny_b + D, yc, hby, lny_g + D, lny_b + D, 1);
            // FFN merged
            ffn1_gemm(xc, fx_w1 + f1o, fx_b1 + f1bo, qkvx,
                      yc, fy_w1 + f1o, fy_b1 + f1bo, qkvy, 2);
            ffn2_gemm(qkvx, fx_w2 + f2o, fx_b2 + f2bo, hbx,
                      qkvy, fy_w2 + f2o, fy_b2 + f2bo, hby, 2);
            ln(xc, hbx, lnx_g + 2 * D, lnx_b + 2 * D,
               yc, hby, lny_g + 2 * D, lny_b + 2 * D, 2);
        } else {
            // sequential fallback (aliased buffers)
            qkv_gemm(xc, xc, ax_w + wo, ax_b + bo, qkvx, xc, xc, ax_w + wo, ax_b + bo, qkvx, 1);
            attn(qkvx, xm, hbx, qkvx, xm, hbx, 1);
            ln(xc, hbx, lnx_g, lnx_b, xc, hbx, lnx_g, lnx_b, 1);
            qkv_gemm(yc, yc, ay_w + wo, ay_b + bo, qkvy, yc, yc, ay_w + wo, ay_b + bo, qkvy, 1);
            attn(qkvy, ym, hby, qkvy, ym, hby, 1);
            ln(yc, hby, lny_g, lny_b, yc, hby, lny_g, lny_b, 1);
            qkv_gemm(xc, yc, cx_w + wo, cx_b + bo, qkvx, xc, yc, cx_w + wo, cx_b + bo, qkvx, 1);
            attn(qkvx, ym, hbx, qkvx, ym, hbx, 1);
            ln(xc, hbx, lnx_g + D, lnx_b + D, xc, hbx, lnx_g + D, lnx_b + D, 1);
            qkv_gemm(yc, xc, cy_w + wo, cy_b + bo, qkvy, yc, xc, cy_w + wo, cy_b + bo, qkvy, 1);
            attn(qkvy, xm, hby, qkvy, xm, hby, 1);
            ln(yc, hby, lny_g + D, lny_b + D, yc, hby, lny_g + D, lny_b + D, 1);
            ffn1_gemm(xc, fx_w1 + f1o, fx_b1 + f1bo, qkvx, xc, fx_w1 + f1o, fx_b1 + f1bo, qkvx, 1);
            ffn2_gemm(qkvx, fx_w2 + f2o, fx_b2 + f2bo, hbx, qkvx, fx_w2 + f2o, fx_b2 + f2bo, hbx, 1);
            ln(xc, hbx, lnx_g + 2 * D, lnx_b + 2 * D, xc, hbx, lnx_g + 2 * D, lnx_b + 2 * D, 1);
            ffn1_gemm(yc, fy_w1 + f1o, fy_b1 + f1bo, qkvy, yc, fy_w1 + f1o, fy_b1 + f1bo, qkvy, 1);
            ffn2_gemm(qkvy, fy_w2 + f2o, fy_b2 + f2bo, hby, qkvy, fy_w2 + f2o, fy_b2 + f2bo, hby, 1);
            ln(yc, hby, lny_g + 2 * D, lny_b + 2 * D, yc, hby, lny_g + 2 * D, lny_b + 2 * D, 1);
        }
    }
}